// Round 9
// baseline (1215.456 us; speedup 1.0000x reference)
//
#include <hip/hip_runtime.h>

// ---------------------------------------------------------------------------
// Two-layer tanh RNN — round 11: L3-resident ring + non-temporal streams.
// B=64, T=512, H=512, I=128, W_OUT=32. fp32 in/out, f16 internal, fp32 acc.
//
// Base = round-10 (MFMA core on the R7 exchange skeleton; verified). Theory:
// step time is a latency chain whose straggler is an HBM-miss poll — the
// 33.5MB hb0 ring + 134MB once-through noise thrash L3, so ~6 polled lines
// per WG-step fall to HBM (~900cy) and the max-over-slots gate pays it every
// step. Round-11 deltas:
//  (1) DRING 256->32: hb0 = 4.2MB, L3-resident. THR_LEAD 20 (<32 horizon,
//      ~4-step staleness margin; same throttle proof as before).
//  (2) noise/x loads are NON-TEMPORAL (read-once streams stop evicting the
//      hot ring window from L2/L3).
//  (3) poll1 double-pumps (2 overlapped loads per retry) — halves detect
//      quantization.
//  (4) plain s_barrier before the bottom remote-prefetch so it samples after
//      the reduce posts (R8's prefetch raced the posts and was always stale).
// Everything else verbatim R10: MFMA 16x16x32 f16 (A=weights in VGPRs, B=h
// frags from flat LDS hflat[parity][batch][pair], cols 0/1 = batches), psum
// reduce, tagged {tag32|f16pair} atoms RELAXED agent scope, epoch tags, h0
// prefetch pipeline, lgkm-only barriers, FC epilogue in L1 s==0.
// ---------------------------------------------------------------------------

#define T_STEPS 512
#define NBATCH  64
#define DRING   32
#define THR_LEAD 20

typedef _Float16 half2v __attribute__((ext_vector_type(2)));
typedef _Float16 f16x8  __attribute__((ext_vector_type(8)));
typedef float    f32x4  __attribute__((ext_vector_type(4)));

__device__ __forceinline__ unsigned pack2(float a, float b) {
    _Float16 fa = (_Float16)a, fb = (_Float16)b;
    unsigned short ua = __builtin_bit_cast(unsigned short, fa);
    unsigned short ub = __builtin_bit_cast(unsigned short, fb);
    return (unsigned)ua | ((unsigned)ub << 16);
}

__device__ __forceinline__ float fast_tanh(float xv) {
    float e2 = __builtin_amdgcn_exp2f(xv * 2.885390082f);
    return 1.f - 2.f * __builtin_amdgcn_rcpf(e2 + 1.f);
}

__device__ __forceinline__ f32x4 mfma16(uint4 a, uint4 b, f32x4 c) {
    return __builtin_amdgcn_mfma_f32_16x16x32_f16(
        __builtin_bit_cast(f16x8, a), __builtin_bit_cast(f16x8, b), c, 0, 0, 0);
}

// Workgroup barrier with LDS-only drain (posts/prefetches stay in flight).
__device__ __forceinline__ void bar_lgkm() {
    asm volatile("s_waitcnt lgkmcnt(0)\n\ts_barrier" ::: "memory");
}

// Non-temporal stream loads (noise/x are read exactly once — keep them out
// of L2/L3 so the exchange rings stay cache-resident).
__device__ __forceinline__ float ntload_f(const float* p) {
    return __builtin_nontemporal_load(p);
}
__device__ __forceinline__ float2 ntload_f2(const float* p) {
    float a = __builtin_nontemporal_load(p);
    float b = __builtin_nontemporal_load(p + 1);
    return make_float2(a, b);
}

// Double-pumped tagged poll: two overlapped loads per retry.
__device__ __forceinline__ unsigned poll1(unsigned long long* p, unsigned tag,
                                          long& budget) {
    unsigned long long v = __hip_atomic_load(p, __ATOMIC_RELAXED, __HIP_MEMORY_SCOPE_AGENT);
    while ((unsigned)(v >> 32) != tag && budget > 0) {
        unsigned long long a = __hip_atomic_load(p, __ATOMIC_RELAXED, __HIP_MEMORY_SCOPE_AGENT);
        unsigned long long b = __hip_atomic_load(p, __ATOMIC_RELAXED, __HIP_MEMORY_SCOPE_AGENT);
        v = ((unsigned)(a >> 32) == tag) ? a : b;
        --budget;
    }
    return (unsigned)v;
}

// A-fragment weight packs: wp[((s*16 + w)*16 + f)*64 + lane] (uint4).
// L0: wave w: kc=w>>2, rg=w&3; frag f = j*5+ktl (j<2 row-tiles, ktl<5), f>=10 zero.
// L1: wave w: kc=w>>1, rg=w&1; frag f = j*4+ktl (j<4, ktl<4).
// Element: row r = s*128 + (rg*RT+j)*16 + (lane&15);
//          pair kp = kc*KCP + ktl*16 + (lane>>4)*4 + d  (d=0..3; k=2*kp).
// L0 pair-space: kp<64 = x, else h0 pair kp-64. L1: kp<256 = h0, else h1 kp-256.
#define NWPF (4 * 16 * 16 * 64)

__global__ void init_pack(const float* __restrict__ Wih0, const float* __restrict__ Whh0,
                          const float* __restrict__ Wih1, const float* __restrict__ Whh1,
                          uint4* __restrict__ wp0, uint4* __restrict__ wp1,
                          int* __restrict__ prog) {
    int gid = blockIdx.x * 256 + threadIdx.x;
    if (gid == 32) prog[32] = prog[32] + 1;   // epoch bump (replay-unique tags)
    if (gid < 32) prog[gid] = 0;
    if (gid < NWPF) {
        int lane = gid & 63, f = (gid >> 6) & 15, w = (gid >> 10) & 15, s = gid >> 14;
        uint4 o = make_uint4(0, 0, 0, 0);
        if (f < 10) {
            int kc = w >> 2, rg = w & 3, j = f / 5, ktl = f % 5;
            int r = s * 128 + (rg * 2 + j) * 16 + (lane & 15);
            unsigned dv[4];
#pragma unroll
            for (int d = 0; d < 4; ++d) {
                int kp = kc * 80 + ktl * 16 + ((lane >> 4) * 4) + d;
                float w0, w1;
                if (kp < 64) { w0 = Wih0[r * 128 + 2 * kp]; w1 = Wih0[r * 128 + 2 * kp + 1]; }
                else { int p0 = kp - 64;
                       w0 = Whh0[r * 512 + 2 * p0]; w1 = Whh0[r * 512 + 2 * p0 + 1]; }
                dv[d] = pack2(w0, w1);
            }
            o = make_uint4(dv[0], dv[1], dv[2], dv[3]);
        }
        wp0[gid] = o;
    } else if (gid < 2 * NWPF) {
        int idx = gid - NWPF;
        int lane = idx & 63, f = (idx >> 6) & 15, w = (idx >> 10) & 15, s = idx >> 14;
        int kc = w >> 1, rg = w & 1, j = f >> 2, ktl = f & 3;
        int r = s * 128 + (rg * 4 + j) * 16 + (lane & 15);
        unsigned dv[4];
#pragma unroll
        for (int d = 0; d < 4; ++d) {
            int kp = kc * 64 + ktl * 16 + ((lane >> 4) * 4) + d;
            float w0, w1;
            if (kp < 256) { w0 = Wih1[r * 512 + 2 * kp]; w1 = Wih1[r * 512 + 2 * kp + 1]; }
            else { int p1 = kp - 256;
                   w0 = Whh1[r * 512 + 2 * p1]; w1 = Whh1[r * 512 + 2 * p1 + 1]; }
            dv[d] = pack2(w0, w1);
        }
        wp1[idx] = make_uint4(dv[0], dv[1], dv[2], dv[3]);
    }
}

template <int LAYER>
__device__ __forceinline__ void run_layer(
    int b0, int s, int L, int pair,
    const float* __restrict__ x, const float* __restrict__ noise,
    const uint4* __restrict__ wp,
    const float* __restrict__ bih, const float* __restrict__ bhh,
    unsigned long long* __restrict__ hb0, unsigned long long* __restrict__ hb1,
    int* __restrict__ prog,
    const float* __restrict__ fcw, const float* __restrict__ fcb,
    float* __restrict__ out) {
    constexpr int KC    = (LAYER == 0) ? 4 : 8;     // k-chunks
    constexpr int KT    = (LAYER == 0) ? 5 : 4;     // k-tiles (of 32) per chunk
    constexpr int RT    = (LAYER == 0) ? 2 : 4;     // row-tiles per wave
    constexpr int NPAIR = (LAYER == 0) ? 320 : 512; // flat pair space
    constexpr int OWNB  = (LAYER == 0) ? 64 : 256;  // own-h base in pair space
    constexpr int NF    = (LAYER == 0) ? 10 : 16;   // A-frags per wave
    constexpr int KCP   = (LAYER == 0) ? 80 : 64;   // pairs per chunk

    const int w = L >> 6, lane = L & 63;
    const unsigned tagbase = ((unsigned)prog[32]) << 10;
    long budget = 2000000000L;

    // ---- persistent A-fragments ----
    uint4 wfr[NF];
#pragma unroll
    for (int f = 0; f < NF; ++f) {
        wfr[f] = wp[(size_t)(((s * 16 + w) * 16) + f) * 64 + lane];
        asm volatile("" : "+v"(wfr[f].x), "+v"(wfr[f].y), "+v"(wfr[f].z), "+v"(wfr[f].w));
    }

    __shared__ __align__(16) unsigned hflat[2][2][NPAIR];  // [parity][batch][pair]
    __shared__ __align__(16) float psum[2][KC][2][128];    // [parity][kc][batch][row]
    for (int i = L; i < 2 * 2 * NPAIR; i += 1024) ((unsigned*)hflat)[i] = 0u;  // h(-1)=0

    // reduce-role constants (lanes 0..255: bb = L>>7, row rw = L&127)
    const bool isRed = (L < 256);
    const int bbr = L >> 7, rw = L & 127;
    const int rgl = s * 128 + rw;
    float cb = 0.f, nz = 0.f;
    if (isRed) {
        cb = bih[rgl] + bhh[rgl];
        nz = ntload_f(&noise[(((size_t)(b0 + bbr) * T_STEPS + 0) * 2 + LAYER) * 512 + rgl]);
    }
    __syncthreads();

    unsigned long long pf = 0;    // L1 w<8: h0 prefetch
    unsigned long long pfR = 0;   // remote-h prefetch
    float2 xf = make_float2(0.f, 0.f);
    if constexpr (LAYER == 0) {
        if (w >= 14) {
            int j = lane & 31, bbl = lane >> 5, px = (w - 14) * 32 + j;
            xf = ntload_f2(x + ((size_t)(b0 + bbl) * T_STEPS + 0) * 128 + 2 * px);
        }
    }

    int known = 0;
    const int colm = lane & 15, kg = lane >> 4;
    const int kcv = (LAYER == 0) ? (w >> 2) : (w >> 1);
    const int rg  = (LAYER == 0) ? (w & 3)  : (w & 1);

    for (int t = 0; t < T_STEPS; ++t) {
        const int p = t & 1;
        const bool last = (t == T_STEPS - 1);
        __builtin_amdgcn_s_setprio(1);

        // ---- STAGE: fill hflat[p] (1 dword/lane roles) ----
        if constexpr (LAYER == 1) {
            if (w < 8) {                                  // h0(t) via pf pipeline
                const int j = lane & 31, bbl = lane >> 5;
                unsigned want = tagbase + (unsigned)t + 1;
                if ((unsigned)(pf >> 32) != want) {
                    __builtin_amdgcn_s_setprio(0);
                    unsigned v = poll1(&hb0[((size_t)(t & (DRING - 1)) * NBATCH + (b0 + bbl)) * 256 +
                                            (w * 32 + j)], want, budget);
                    pf = ((unsigned long long)want << 32) | v;
                    __builtin_amdgcn_s_setprio(1);
                }
                hflat[p][bbl][w * 32 + j] = (unsigned)pf;
                if (!last)
                    pf = __hip_atomic_load(&hb0[((size_t)((t + 1) & (DRING - 1)) * NBATCH +
                                                 (b0 + bbl)) * 256 + (w * 32 + j)],
                                           __ATOMIC_RELAXED, __HIP_MEMORY_SCOPE_AGENT);
            } else if (w >= 10) {                         // remote h1(t-1)
                if (t > 0) {
                    const int j = lane & 31, bbl = lane >> 5;
                    int m = (w - 10) * 32 + j;
                    int p2 = (m < s * 64) ? m : m + 64;
                    unsigned want = tagbase + (unsigned)t;
                    unsigned v;
                    if ((unsigned)(pfR >> 32) == want) v = (unsigned)pfR;
                    else {
                        __builtin_amdgcn_s_setprio(0);
                        v = poll1(&hb1[((size_t)((t - 1) & 3) * NBATCH + (b0 + bbl)) * 256 + p2],
                                  want, budget);
                        __builtin_amdgcn_s_setprio(1);
                    }
                    hflat[p][bbl][256 + p2] = v;
                }
            }
        } else {
            if (w >= 8 && w < 14) {                       // remote h0(t-1): 6 waves x 64
                if (t > 0) {
                    int idx = (w - 8) * 64 + lane;
                    int bbl = (idx >= 192) ? 1 : 0;
                    int m = idx - bbl * 192;
                    int p2 = (m < s * 64) ? m : m + 64;
                    unsigned want = tagbase + (unsigned)t;
                    unsigned v;
                    if ((unsigned)(pfR >> 32) == want) v = (unsigned)pfR;
                    else {
                        __builtin_amdgcn_s_setprio(0);
                        v = poll1(&hb0[((size_t)((t - 1) & (DRING - 1)) * NBATCH +
                                        (b0 + bbl)) * 256 + p2],
                                  want, budget);
                        __builtin_amdgcn_s_setprio(1);
                    }
                    hflat[p][bbl][64 + p2] = v;
                }
            } else if (w >= 14) {                         // x(t) pack + x(t+1) nt-load
                const int j = lane & 31, bbl = lane >> 5, px = (w - 14) * 32 + j;
                hflat[p][bbl][px] = pack2(xf.x, xf.y);
                if (!last)
                    xf = ntload_f2(x + ((size_t)(b0 + bbl) * T_STEPS + (t + 1)) * 128 + 2 * px);
            }
        }

        float nznext = 0.f;
        if (!last && isRed)
            nznext = ntload_f(&noise[(((size_t)(b0 + bbr) * T_STEPS + (t + 1)) * 2 + LAYER) * 512 + rgl]);

        bar_lgkm();                                       // bar_s: hflat[p] sealed

        // ---- MFMA dots: B shared across RT row-tiles ----
        {
            uint4 Bfr[KT];
            const unsigned* hbase = &hflat[p][colm & 1][kcv * KCP + kg * 4];
#pragma unroll
            for (int ktl = 0; ktl < KT; ++ktl)
                Bfr[ktl] = *(const uint4*)&hbase[ktl * 16];
#pragma unroll
            for (int j = 0; j < RT; ++j) {
                f32x4 C = {0.f, 0.f, 0.f, 0.f};
#pragma unroll
                for (int ktl = 0; ktl < KT; ++ktl)
                    C = mfma16(wfr[j * KT + ktl], Bfr[ktl], C);
                if (colm < 2)
                    *(f32x4*)&psum[p][kcv][colm][(rg * RT + j) * 16 + 4 * kg] = C;
            }
        }

        bar_lgkm();                                       // bar_b: psum ready

        // ---- reduce + tanh + post + own write into hflat[p^1] ----
        if (isRed) {
            float sum = 0.f;
#pragma unroll
            for (int c2 = 0; c2 < KC; ++c2) sum += psum[p][c2][bbr][rw];
            float h = fast_tanh(sum + cb + nz);
            float hnb = __shfl_down(h, 1);
            if ((L & 1) == 0) {
                unsigned pv = pack2(h, hnb);
                int pr = s * 64 + (rw >> 1);
                unsigned long long atom =
                    ((unsigned long long)(tagbase + (unsigned)t + 1) << 32) |
                    (unsigned long long)pv;
                if constexpr (LAYER == 0) {
                    if (t - known > THR_LEAD) {           // ring-overwrite throttle
                        __builtin_amdgcn_s_setprio(0);
                        while (t - known > THR_LEAD && budget > 0) {
                            known = __hip_atomic_load(&prog[pair], __ATOMIC_RELAXED,
                                                      __HIP_MEMORY_SCOPE_AGENT);
                            --budget;
                        }
                        __builtin_amdgcn_s_setprio(1);
                    }
                    __hip_atomic_store(&hb0[((size_t)(t & (DRING - 1)) * NBATCH + (b0 + bbr)) * 256 + pr],
                                       atom, __ATOMIC_RELAXED, __HIP_MEMORY_SCOPE_AGENT);
                } else {
                    __hip_atomic_store(&hb1[((size_t)(t & 3) * NBATCH + (b0 + bbr)) * 256 + pr],
                                       atom, __ATOMIC_RELAXED, __HIP_MEMORY_SCOPE_AGENT);
                }
                hflat[p ^ 1][bbr][OWNB + s * 64 + (rw >> 1)] = pv;
            }
            nz = nznext;
        }
        if constexpr (LAYER == 1) {                       // consumer progress
            if (s == 0 && L == 960 && t > 1)
                __hip_atomic_store(&prog[pair], t - 2, __ATOMIC_RELAXED,
                                   __HIP_MEMORY_SCOPE_AGENT);
        }
        __builtin_amdgcn_s_setprio(0);

        // ---- bottom: prefetch remote for t+1 (after posts issued) ----
        if (!last) {
            __builtin_amdgcn_s_barrier();                 // align prefetch after posts
            if constexpr (LAYER == 1) {
                if (w >= 10) {
                    const int j = lane & 31, bbl = lane >> 5;
                    int m = (w - 10) * 32 + j;
                    int p2 = (m < s * 64) ? m : m + 64;
                    pfR = __hip_atomic_load(&hb1[((size_t)(t & 3) * NBATCH + (b0 + bbl)) * 256 + p2],
                                            __ATOMIC_RELAXED, __HIP_MEMORY_SCOPE_AGENT);
                }
            } else {
                if (w >= 8 && w < 14) {
                    int idx = (w - 8) * 64 + lane;
                    int bbl = (idx >= 192) ? 1 : 0;
                    int m = idx - bbl * 192;
                    int p2 = (m < s * 64) ? m : m + 64;
                    pfR = __hip_atomic_load(&hb0[((size_t)(t & (DRING - 1)) * NBATCH +
                                                  (b0 + bbl)) * 256 + p2],
                                            __ATOMIC_RELAXED, __HIP_MEMORY_SCOPE_AGENT);
                }
            }
        }
    }

    // ---- FC epilogue: out = h1(T-1) @ fc_w^T + fc_b (L1 s==0 WGs) ----
    if constexpr (LAYER == 1) {
        if (s == 0) {
            __shared__ float hs[2][512];
            __shared__ float part[2][512];
            if (L < 512) {
                int bl = L >> 8, pr = L & 255;
                unsigned v = poll1(&hb1[((size_t)((T_STEPS - 1) & 3) * NBATCH + (b0 + bl)) * 256 + pr],
                                   tagbase + (unsigned)T_STEPS, budget);
                half2v h2 = __builtin_bit_cast(half2v, v);
                hs[bl][2 * pr] = (float)h2.x; hs[bl][2 * pr + 1] = (float)h2.y;
            }
            __syncthreads();
            {
                int bl = L >> 9, rest = L & 511, o = rest & 31, seg = rest >> 5;
                const float* wr = fcw + o * 512 + seg * 32;
                const float* hr = &hs[bl][seg * 32];
                float a = 0.f;
#pragma unroll
                for (int k = 0; k < 32; ++k) a = fmaf(wr[k], hr[k], a);
                part[bl][rest] = a;
            }
            __syncthreads();
            if (L < 64) {
                int bl = L >> 5, o = L & 31;
                float ssum = fcb[o];
#pragma unroll
                for (int sgi = 0; sgi < 16; ++sgi) ssum += part[bl][sgi * 32 + o];
                out[(b0 + bl) * 32 + o] = ssum;
            }
        }
    }
}

__global__ __launch_bounds__(1024, 4)
void rnn_dual(const float* __restrict__ x, const float* __restrict__ noise,
              const uint4* __restrict__ wp0, const uint4* __restrict__ wp1,
              const float* __restrict__ bih0, const float* __restrict__ bhh0,
              const float* __restrict__ bih1, const float* __restrict__ bhh1,
              const float* __restrict__ fcw, const float* __restrict__ fcb,
              unsigned long long* __restrict__ hb0,
              unsigned long long* __restrict__ hb1,
              int* __restrict__ prog,
              float* __restrict__ out) {
    const int L = threadIdx.x;
    const int gid = blockIdx.x;
    const int cl = gid & 63;             // cluster: layer*32 + pair
    const int s = gid >> 6;              // sibling quarter 0..3
    const int layer = cl >> 5;
    const int pair = cl & 31;
    const int b0 = pair * 2;             // gid%8 == cl%8: co-XCD (locality only)
    if (layer == 0)
        run_layer<0>(b0, s, L, pair, x, noise, wp0, bih0, bhh0,
                     hb0, hb1, prog, nullptr, nullptr, nullptr);
    else
        run_layer<1>(b0, s, L, pair, x, noise, wp1, bih1, bhh1,
                     hb0, hb1, prog, fcw, fcb, out);
}

extern "C" void kernel_launch(void* const* d_in, const int* in_sizes, int n_in,
                              void* d_out, int out_size, void* d_ws, size_t ws_size,
                              hipStream_t stream) {
    const float* x     = (const float*)d_in[0];
    const float* noise = (const float*)d_in[1];
    const float* Wih0  = (const float*)d_in[2];
    const float* Wih1  = (const float*)d_in[3];
    const float* Whh0  = (const float*)d_in[4];
    const float* Whh1  = (const float*)d_in[5];
    const float* bih0  = (const float*)d_in[6];
    const float* bih1  = (const float*)d_in[7];
    const float* bhh0  = (const float*)d_in[8];
    const float* bhh1  = (const float*)d_in[9];
    const float* fcw   = (const float*)d_in[10];
    const float* fcb   = (const float*)d_in[11];
    float* out = (float*)d_out;

    char* ws = (char*)d_ws;
    size_t o = 0;
    uint4* wp0 = (uint4*)(ws + o); o += (size_t)NWPF * 16;      // 1 MB
    uint4* wp1 = (uint4*)(ws + o); o += (size_t)NWPF * 16;      // 1 MB
    unsigned long long* hb0 = (unsigned long long*)(ws + o);
    o += (size_t)DRING * NBATCH * 256 * 8;                      // 4.2 MB ring (L3-hot)
    unsigned long long* hb1 = (unsigned long long*)(ws + o);
    o += (size_t)4 * NBATCH * 256 * 8;                          // 512 KB ring
    int* prog = (int*)(ws + o); o += 33 * sizeof(int);          // prog + epoch

    const int total = 2 * NWPF;
    init_pack<<<(total + 255) / 256, 256, 0, stream>>>(Wih0, Whh0, Wih1, Whh1,
                                                       wp0, wp1, prog);
    rnn_dual<<<256, 1024, 0, stream>>>(x, noise, wp0, wp1, bih0, bhh0, bih1, bhh1,
                                       fcw, fcb, hb0, hb1, prog, out);
}

// Round 10
// 1195.819 us; speedup vs baseline: 1.0164x; 1.0164x over previous
//
#include <hip/hip_runtime.h>

// ---------------------------------------------------------------------------
// Two-layer tanh RNN — round 12: chunk-owner waves (stage->own-MFMA, no bar_s).
// B=64, T=512, H=512, I=128, W_OUT=32. fp32 in/out, f16 internal, fp32 acc.
//
// Exchange verbatim from R9 champion lineage: 64 clusters = {layer}x{pair},
// 4 sibling WGs x 1024 thr, 1 WG/CU; tagged {tag32|f16pair} atoms RELAXED
// agent scope; hb0 DRING=32 + consumer-progress throttle; hb1 4-ring; epoch
// tags; L1 h0 prefetch pipeline; nt loads for x/noise; FC in L1 s==0.
//
// NEW compute structure (the R6-overlap x R8-MFMA combination):
//   Wave w OWNS k-pair block 32w..32w+31 (2 k-tiles x 2 batches = 64 dwords):
//   it stages that block into its PRIVATE LDS strip (1 poll/lane max) and
//   immediately MFMAs it over all 8 row-tiles (within-wave LDS write->read:
//   no barrier). Ready waves (x / pf-h0 / own-h filled by last reduce) start
//   MFMAs instantly; remote-h waves poll concurrently. The old bar_s (which
//   serialized EVERY MFMA behind the slowest remote detect) is GONE.
//   Barriers/step: bar_b (psum ready) + bar_c (own-strip writes + psum WAR).
// Roles L0 (K=640=20 tiles): w0-1 x, w2-9 h0 (own: 2+2s,3+2s), w10-15 idle.
// Roles L1 (K=1024=32 tiles): w0-7 h0 (pf pipeline), w8-15 h1 (own: 8+2s,9+2s).
// psum[NP][2][128], NP=10/16; reduce lanes 0-255 sum + tanh + post + write
// own pairs into the OWNER waves' strips (sealed by bar_c).
// A/B fragment k-formula identical on both operands (R8 correctness-verified).
// ---------------------------------------------------------------------------

#define T_STEPS 512
#define NBATCH  64
#define DRING   32
#define THR_LEAD 20

typedef _Float16 half2v __attribute__((ext_vector_type(2)));
typedef _Float16 f16x8  __attribute__((ext_vector_type(8)));
typedef float    f32x4  __attribute__((ext_vector_type(4)));

__device__ __forceinline__ unsigned pack2(float a, float b) {
    _Float16 fa = (_Float16)a, fb = (_Float16)b;
    unsigned short ua = __builtin_bit_cast(unsigned short, fa);
    unsigned short ub = __builtin_bit_cast(unsigned short, fb);
    return (unsigned)ua | ((unsigned)ub << 16);
}

__device__ __forceinline__ float fast_tanh(float xv) {
    float e2 = __builtin_amdgcn_exp2f(xv * 2.885390082f);
    return 1.f - 2.f * __builtin_amdgcn_rcpf(e2 + 1.f);
}

__device__ __forceinline__ f32x4 mfma16(uint4 a, uint4 b, f32x4 c) {
    return __builtin_amdgcn_mfma_f32_16x16x32_f16(
        __builtin_bit_cast(f16x8, a), __builtin_bit_cast(f16x8, b), c, 0, 0, 0);
}

// Workgroup barrier with LDS-only drain (posts/prefetches stay in flight).
__device__ __forceinline__ void bar_lgkm() {
    asm volatile("s_waitcnt lgkmcnt(0)\n\ts_barrier" ::: "memory");
}

__device__ __forceinline__ float ntload_f(const float* p) {
    return __builtin_nontemporal_load(p);
}
__device__ __forceinline__ float2 ntload_f2(const float* p) {
    float a = __builtin_nontemporal_load(p);
    float b = __builtin_nontemporal_load(p + 1);
    return make_float2(a, b);
}

// Double-pumped tagged poll.
__device__ __forceinline__ unsigned poll1(unsigned long long* p, unsigned tag,
                                          long& budget) {
    unsigned long long v = __hip_atomic_load(p, __ATOMIC_RELAXED, __HIP_MEMORY_SCOPE_AGENT);
    while ((unsigned)(v >> 32) != tag && budget > 0) {
        unsigned long long a = __hip_atomic_load(p, __ATOMIC_RELAXED, __HIP_MEMORY_SCOPE_AGENT);
        unsigned long long b = __hip_atomic_load(p, __ATOMIC_RELAXED, __HIP_MEMORY_SCOPE_AGENT);
        v = ((unsigned)(a >> 32) == tag) ? a : b;
        --budget;
    }
    return (unsigned)v;
}

// A-fragment packs: wp[((s*16+w)*16 + f)*64 + lane], f = rt*2 + ktl.
// row r = s*128 + rt*16 + (lane&15); pair kp = 32w + ktl*16 + (lane>>4)*4 + d.
// L0 (w<10): kp<64 -> x pair kp (Wih0), else h0 pair kp-64 (Whh0); w>=10 zero.
// L1: kp<256 -> Wih1, else Whh1 (kp-256).
#define NWPF (4 * 16 * 16 * 64)

__global__ void init_pack(const float* __restrict__ Wih0, const float* __restrict__ Whh0,
                          const float* __restrict__ Wih1, const float* __restrict__ Whh1,
                          uint4* __restrict__ wp0, uint4* __restrict__ wp1,
                          int* __restrict__ prog) {
    int gid = blockIdx.x * 256 + threadIdx.x;
    if (gid == 32) prog[32] = prog[32] + 1;   // epoch bump (replay-unique tags)
    if (gid < 32) prog[gid] = 0;
    if (gid < NWPF) {
        int lane = gid & 63, f = (gid >> 6) & 15, w = (gid >> 10) & 15, s = gid >> 14;
        uint4 o = make_uint4(0, 0, 0, 0);
        if (w < 10) {
            int rt = f >> 1, ktl = f & 1;
            int r = s * 128 + rt * 16 + (lane & 15);
            unsigned dv[4];
#pragma unroll
            for (int d = 0; d < 4; ++d) {
                int kp = 32 * w + ktl * 16 + ((lane >> 4) * 4) + d;
                float w0, w1;
                if (kp < 64) { w0 = Wih0[r * 128 + 2 * kp]; w1 = Wih0[r * 128 + 2 * kp + 1]; }
                else { int p0 = kp - 64;
                       w0 = Whh0[r * 512 + 2 * p0]; w1 = Whh0[r * 512 + 2 * p0 + 1]; }
                dv[d] = pack2(w0, w1);
            }
            o = make_uint4(dv[0], dv[1], dv[2], dv[3]);
        }
        wp0[gid] = o;
    } else if (gid < 2 * NWPF) {
        int idx = gid - NWPF;
        int lane = idx & 63, f = (idx >> 6) & 15, w = (idx >> 10) & 15, s = idx >> 14;
        int rt = f >> 1, ktl = f & 1;
        int r = s * 128 + rt * 16 + (lane & 15);
        unsigned dv[4];
#pragma unroll
        for (int d = 0; d < 4; ++d) {
            int kp = 32 * w + ktl * 16 + ((lane >> 4) * 4) + d;
            float w0, w1;
            if (kp < 256) { w0 = Wih1[r * 512 + 2 * kp]; w1 = Wih1[r * 512 + 2 * kp + 1]; }
            else { int p1 = kp - 256;
                   w0 = Whh1[r * 512 + 2 * p1]; w1 = Whh1[r * 512 + 2 * p1 + 1]; }
            dv[d] = pack2(w0, w1);
        }
        wp1[idx] = make_uint4(dv[0], dv[1], dv[2], dv[3]);
    }
}

template <int LAYER>
__device__ __forceinline__ void run_layer(
    int b0, int s, int L, int pair,
    const float* __restrict__ x, const float* __restrict__ noise,
    const uint4* __restrict__ wp,
    const float* __restrict__ bih, const float* __restrict__ bhh,
    unsigned long long* __restrict__ hb0, unsigned long long* __restrict__ hb1,
    int* __restrict__ prog,
    const float* __restrict__ fcw, const float* __restrict__ fcb,
    float* __restrict__ out) {
    constexpr int NP = (LAYER == 0) ? 10 : 16;      // active waves / psum groups

    const int w = L >> 6, lane = L & 63;
    const int j31 = lane & 31, bbl = lane >> 5;     // stage sub-roles
    const unsigned tagbase = ((unsigned)prog[32]) << 10;
    long budget = 2000000000L;

    // role flags (wave-uniform)
    const bool active   = (LAYER == 1) || (w < 10);
    const bool isX      = (LAYER == 0) && (w < 2);
    const bool isPF     = (LAYER == 1) && (w < 8);
    const bool isOwn    = (LAYER == 0) ? (w == 2 + 2 * s || w == 3 + 2 * s)
                                       : (w == 8 + 2 * s || w == 9 + 2 * s);
    const bool isRemote = active && !isX && !isPF && !isOwn;

    // ---- persistent A-fragments (16 x uint4 = 64 VGPRs) ----
    uint4 wfr[16];
#pragma unroll
    for (int f = 0; f < 16; ++f) {
        wfr[f] = wp[(size_t)(((s * 16 + w) * 16) + f) * 64 + lane];
        asm volatile("" : "+v"(wfr[f].x), "+v"(wfr[f].y), "+v"(wfr[f].z), "+v"(wfr[f].w));
    }

    __shared__ __align__(16) unsigned strip[16][64];   // per-wave k-block [b*32 + kp_local]
    __shared__ __align__(16) float psum[NP][2][128];   // [group][batch][row]
    for (int i = L; i < 16 * 64; i += 1024) ((unsigned*)strip)[i] = 0u;  // h(-1)=0

    // reduce-role constants (lanes 0..255)
    const bool isRed = (L < 256);
    const int bbr = L >> 7, rw = L & 127;
    const int rgl = s * 128 + rw;
    float cb = 0.f, nz = 0.f;
    if (isRed) {
        cb = bih[rgl] + bhh[rgl];
        nz = ntload_f(&noise[(((size_t)(b0 + bbr) * T_STEPS + 0) * 2 + LAYER) * 512 + rgl]);
    }
    __syncthreads();

    // ---- pre-loop staging ----
    unsigned long long pf = 0;
    float2 xf = make_float2(0.f, 0.f);
    if constexpr (LAYER == 1) {
        if (isPF) {   // h0(0): blocking poll (L0 computes it in its step 0)
            unsigned v = poll1(&hb0[((size_t)0 * NBATCH + (b0 + bbl)) * 256 + (32 * w + j31)],
                               tagbase + 1, budget);
            pf = ((unsigned long long)(tagbase + 1) << 32) | v;
        }
    } else {
        if (isX)
            xf = ntload_f2(x + ((size_t)(b0 + bbl) * T_STEPS + 0) * 128 + 2 * (32 * w + j31));
    }

    int known = 0;
    const int colm = lane & 15, kg = lane >> 4;

    for (int t = 0; t < T_STEPS; ++t) {
        const bool last = (t == T_STEPS - 1);
        __builtin_amdgcn_s_setprio(1);

        // ---- STAGE own k-block into own strip ----
        if constexpr (LAYER == 1) {
            if (isPF) {                                   // h0(t): pf pipeline
                unsigned want = tagbase + (unsigned)t + 1;
                if ((unsigned)(pf >> 32) != want) {
                    __builtin_amdgcn_s_setprio(0);
                    unsigned v = poll1(&hb0[((size_t)(t & (DRING - 1)) * NBATCH + (b0 + bbl)) * 256 +
                                            (32 * w + j31)], want, budget);
                    pf = ((unsigned long long)want << 32) | v;
                    __builtin_amdgcn_s_setprio(1);
                }
                strip[w][bbl * 32 + j31] = (unsigned)pf;
                if (!last)
                    pf = __hip_atomic_load(&hb0[((size_t)((t + 1) & (DRING - 1)) * NBATCH +
                                                 (b0 + bbl)) * 256 + (32 * w + j31)],
                                           __ATOMIC_RELAXED, __HIP_MEMORY_SCOPE_AGENT);
            } else if (isRemote) {                        // remote h1(t-1)
                if (t > 0) {
                    int p1 = 32 * (w - 8) + j31;
                    __builtin_amdgcn_s_setprio(0);
                    unsigned v = poll1(&hb1[((size_t)((t - 1) & 3) * NBATCH + (b0 + bbl)) * 256 + p1],
                                       tagbase + (unsigned)t, budget);
                    __builtin_amdgcn_s_setprio(1);
                    strip[w][bbl * 32 + j31] = v;
                }
            }                                             // own: filled by reduce(t-1)
        } else {
            if (isX) {                                    // x(t) pack + x(t+1) nt-load
                strip[w][bbl * 32 + j31] = pack2(xf.x, xf.y);
                if (!last)
                    xf = ntload_f2(x + ((size_t)(b0 + bbl) * T_STEPS + (t + 1)) * 128 +
                                   2 * (32 * w + j31));
            } else if (isRemote) {                        // remote h0(t-1)
                if (t > 0) {
                    int p0 = 32 * w - 64 + j31;
                    __builtin_amdgcn_s_setprio(0);
                    unsigned v = poll1(&hb0[((size_t)((t - 1) & (DRING - 1)) * NBATCH +
                                             (b0 + bbl)) * 256 + p0],
                                       tagbase + (unsigned)t, budget);
                    __builtin_amdgcn_s_setprio(1);
                    strip[w][bbl * 32 + j31] = v;
                }
            }                                             // own: filled by reduce(t-1)
        }

        float nznext = 0.f;
        if (!last && isRed)
            nznext = ntload_f(&noise[(((size_t)(b0 + bbr) * T_STEPS + (t + 1)) * 2 + LAYER) * 512 + rgl]);

        // ---- MFMA: this wave's 2 k-tiles over all 8 row-tiles (no bar_s!) ----
        if (active) {
            const unsigned* sb = &strip[w][(colm & 1) * 32 + kg * 4];
            uint4 B0 = *(const uint4*)&sb[0];             // ktl=0 (within-wave w->r order)
            uint4 B1 = *(const uint4*)&sb[16];            // ktl=1
#pragma unroll
            for (int rt = 0; rt < 8; ++rt) {
                f32x4 C = {0.f, 0.f, 0.f, 0.f};
                C = mfma16(wfr[2 * rt + 0], B0, C);
                C = mfma16(wfr[2 * rt + 1], B1, C);
                if (colm < 2)
                    *(f32x4*)&psum[w][colm][rt * 16 + 4 * kg] = C;
            }
        }

        bar_lgkm();                                       // bar_b: psum ready

        // ---- reduce + tanh + post + write own pairs into owner strips ----
        if (isRed) {
            float sum = 0.f;
#pragma unroll
            for (int g = 0; g < NP; ++g) sum += psum[g][bbr][rw];
            float h = fast_tanh(sum + cb + nz);
            float hnb = __shfl_down(h, 1);
            if ((L & 1) == 0) {
                unsigned pv = pack2(h, hnb);
                int pr = s * 64 + (rw >> 1);              // pair index 0..255
                unsigned long long atom =
                    ((unsigned long long)(tagbase + (unsigned)t + 1) << 32) |
                    (unsigned long long)pv;
                if constexpr (LAYER == 0) {
                    if (t - known > THR_LEAD) {           // ring-overwrite throttle
                        __builtin_amdgcn_s_setprio(0);
                        while (t - known > THR_LEAD && budget > 0) {
                            known = __hip_atomic_load(&prog[pair], __ATOMIC_RELAXED,
                                                      __HIP_MEMORY_SCOPE_AGENT);
                            --budget;
                        }
                        __builtin_amdgcn_s_setprio(1);
                    }
                    __hip_atomic_store(&hb0[((size_t)(t & (DRING - 1)) * NBATCH + (b0 + bbr)) * 256 + pr],
                                       atom, __ATOMIC_RELAXED, __HIP_MEMORY_SCOPE_AGENT);
                    strip[2 + (pr >> 5)][bbr * 32 + (pr & 31)] = pv;   // own-h0 owner strip
                } else {
                    __hip_atomic_store(&hb1[((size_t)(t & 3) * NBATCH + (b0 + bbr)) * 256 + pr],
                                       atom, __ATOMIC_RELAXED, __HIP_MEMORY_SCOPE_AGENT);
                    strip[8 + (pr >> 5)][bbr * 32 + (pr & 31)] = pv;   // own-h1 owner strip
                }
            }
            nz = nznext;
        }
        if constexpr (LAYER == 1) {                       // consumer progress
            if (s == 0 && L == 960 && t > 1)
                __hip_atomic_store(&prog[pair], t - 2, __ATOMIC_RELAXED,
                                   __HIP_MEMORY_SCOPE_AGENT);
        }
        bar_lgkm();                                       // bar_c: strips/psum sealed
        __builtin_amdgcn_s_setprio(0);
    }

    // ---- FC epilogue: out = h1(T-1) @ fc_w^T + fc_b (L1 s==0 WGs) ----
    if constexpr (LAYER == 1) {
        if (s == 0) {
            __shared__ float hs[2][512];
            __shared__ float part[2][512];
            if (L < 512) {
                int bl = L >> 8, pr = L & 255;
                unsigned v = poll1(&hb1[((size_t)((T_STEPS - 1) & 3) * NBATCH + (b0 + bl)) * 256 + pr],
                                   tagbase + (unsigned)T_STEPS, budget);
                half2v h2 = __builtin_bit_cast(half2v, v);
                hs[bl][2 * pr] = (float)h2.x; hs[bl][2 * pr + 1] = (float)h2.y;
            }
            __syncthreads();
            {
                int bl = L >> 9, rest = L & 511, o = rest & 31, seg = rest >> 5;
                const float* wr = fcw + o * 512 + seg * 32;
                const float* hr = &hs[bl][seg * 32];
                float a = 0.f;
#pragma unroll
                for (int k = 0; k < 32; ++k) a = fmaf(wr[k], hr[k], a);
                part[bl][rest] = a;
            }
            __syncthreads();
            if (L < 64) {
                int bl = L >> 5, o = L & 31;
                float ssum = fcb[o];
#pragma unroll
                for (int sgi = 0; sgi < 16; ++sgi) ssum += part[bl][sgi * 32 + o];
                out[(b0 + bl) * 32 + o] = ssum;
            }
        }
    }
}

__global__ __launch_bounds__(1024, 4)
void rnn_dual(const float* __restrict__ x, const float* __restrict__ noise,
              const uint4* __restrict__ wp0, const uint4* __restrict__ wp1,
              const float* __restrict__ bih0, const float* __restrict__ bhh0,
              const float* __restrict__ bih1, const float* __restrict__ bhh1,
              const float* __restrict__ fcw, const float* __restrict__ fcb,
              unsigned long long* __restrict__ hb0,
              unsigned long long* __restrict__ hb1,
              int* __restrict__ prog,
              float* __restrict__ out) {
    const int L = threadIdx.x;
    const int gid = blockIdx.x;
    const int cl = gid & 63;             // cluster: layer*32 + pair
    const int s = gid >> 6;              // sibling quarter 0..3
    const int layer = cl >> 5;
    const int pair = cl & 31;
    const int b0 = pair * 2;             // gid%8 == cl%8: co-XCD (locality only)
    if (layer == 0)
        run_layer<0>(b0, s, L, pair, x, noise, wp0, bih0, bhh0,
                     hb0, hb1, prog, nullptr, nullptr, nullptr);
    else
        run_layer<1>(b0, s, L, pair, x, noise, wp1, bih1, bhh1,
                     hb0, hb1, prog, fcw, fcb, out);
}

extern "C" void kernel_launch(void* const* d_in, const int* in_sizes, int n_in,
                              void* d_out, int out_size, void* d_ws, size_t ws_size,
                              hipStream_t stream) {
    const float* x     = (const float*)d_in[0];
    const float* noise = (const float*)d_in[1];
    const float* Wih0  = (const float*)d_in[2];
    const float* Wih1  = (const float*)d_in[3];
    const float* Whh0  = (const float*)d_in[4];
    const float* Whh1  = (const float*)d_in[5];
    const float* bih0  = (const float*)d_in[6];
    const float* bih1  = (const float*)d_in[7];
    const float* bhh0  = (const float*)d_in[8];
    const float* bhh1  = (const float*)d_in[9];
    const float* fcw   = (const float*)d_in[10];
    const float* fcb   = (const float*)d_in[11];
    float* out = (float*)d_out;

    char* ws = (char*)d_ws;
    size_t o = 0;
    uint4* wp0 = (uint4*)(ws + o); o += (size_t)NWPF * 16;      // 1 MB
    uint4* wp1 = (uint4*)(ws + o); o += (size_t)NWPF * 16;      // 1 MB
    unsigned long long* hb0 = (unsigned long long*)(ws + o);
    o += (size_t)DRING * NBATCH * 256 * 8;                      // 4.2 MB ring (L3-hot)
    unsigned long long* hb1 = (unsigned long long*)(ws + o);
    o += (size_t)4 * NBATCH * 256 * 8;                          // 512 KB ring
    int* prog = (int*)(ws + o); o += 33 * sizeof(int);          // prog + epoch

    const int total = 2 * NWPF;
    init_pack<<<(total + 255) / 256, 256, 0, stream>>>(Wih0, Whh0, Wih1, Whh1,
                                                       wp0, wp1, prog);
    rnn_dual<<<256, 1024, 0, stream>>>(x, noise, wp0, wp1, bih0, bhh0, bih1, bhh1,
                                       fcw, fcb, hb0, hb1, prog, out);
}

// Round 11
// 1074.631 us; speedup vs baseline: 1.1310x; 1.1128x over previous
//
#include <hip/hip_runtime.h>

// ---------------------------------------------------------------------------
// Two-layer tanh RNN — round 13: sentinel-paced polling (fabric decongestion).
// B=64, T=512, H=512, I=128, W_OUT=32. fp32 in/out, f16 internal, fp32 acc.
//
// Base = round-12 (chunk-owner waves, MFMA core, verified). Theory: ~6
// spinning waves/WG x 64-addr full-rate polls = ~15 TB/s of agent-scope MALL
// read spam — saturates the fabric and inflates every exchange leg ~3-4x.
// Round-13 deltas (correctness-neutral):
//  (1) poll_sent: wave spins on ONE wave-uniform sentinel slot (1-2 cache
//      lines/retry) paced by s_sleep(1); per-lane tag verify (poll1) runs
//      after sentinel hit (typically 1 attempt). ~64x spin-traffic cut.
//  (2) poll1 single-load retries (double-pump doubled spam).
//  (3) s_sleep(2) pacing in the L0 ring throttle.
// Everything else verbatim R12: wave w owns k-pair block 32w..32w+31, stages
// into private LDS strip, MFMAs immediately (no bar_s); bar_b + bar_c only;
// tagged {tag32|f16pair} atoms RELAXED agent scope; hb0 DRING=32 + throttle;
// hb1 4-ring; epoch tags; L1 h0 prefetch pipeline; nt loads; FC in L1 s==0.
// ---------------------------------------------------------------------------

#define T_STEPS 512
#define NBATCH  64
#define DRING   32
#define THR_LEAD 20

typedef _Float16 half2v __attribute__((ext_vector_type(2)));
typedef _Float16 f16x8  __attribute__((ext_vector_type(8)));
typedef float    f32x4  __attribute__((ext_vector_type(4)));

__device__ __forceinline__ unsigned pack2(float a, float b) {
    _Float16 fa = (_Float16)a, fb = (_Float16)b;
    unsigned short ua = __builtin_bit_cast(unsigned short, fa);
    unsigned short ub = __builtin_bit_cast(unsigned short, fb);
    return (unsigned)ua | ((unsigned)ub << 16);
}

__device__ __forceinline__ float fast_tanh(float xv) {
    float e2 = __builtin_amdgcn_exp2f(xv * 2.885390082f);
    return 1.f - 2.f * __builtin_amdgcn_rcpf(e2 + 1.f);
}

__device__ __forceinline__ f32x4 mfma16(uint4 a, uint4 b, f32x4 c) {
    return __builtin_amdgcn_mfma_f32_16x16x32_f16(
        __builtin_bit_cast(f16x8, a), __builtin_bit_cast(f16x8, b), c, 0, 0, 0);
}

// Workgroup barrier with LDS-only drain (posts/prefetches stay in flight).
__device__ __forceinline__ void bar_lgkm() {
    asm volatile("s_waitcnt lgkmcnt(0)\n\ts_barrier" ::: "memory");
}

__device__ __forceinline__ float ntload_f(const float* p) {
    return __builtin_nontemporal_load(p);
}
__device__ __forceinline__ float2 ntload_f2(const float* p) {
    float a = __builtin_nontemporal_load(p);
    float b = __builtin_nontemporal_load(p + 1);
    return make_float2(a, b);
}

// Per-lane tag verify: single-load retries (no sleep — used post-sentinel).
__device__ __forceinline__ unsigned poll1(unsigned long long* p, unsigned tag,
                                          long& budget) {
    unsigned long long v = __hip_atomic_load(p, __ATOMIC_RELAXED, __HIP_MEMORY_SCOPE_AGENT);
    while ((unsigned)(v >> 32) != tag && budget > 0) {
        v = __hip_atomic_load(p, __ATOMIC_RELAXED, __HIP_MEMORY_SCOPE_AGENT);
        --budget;
    }
    return (unsigned)v;
}

// Sentinel-paced wave poll: spin on ONE wave-uniform slot (s_sleep-paced,
// 1-2 cache lines per retry), then per-lane verify (typically 1 attempt).
__device__ __forceinline__ unsigned poll_sent(unsigned long long* p,
                                              unsigned long long* sent,
                                              unsigned tag, long& budget) {
    unsigned long long sv = __hip_atomic_load(sent, __ATOMIC_RELAXED, __HIP_MEMORY_SCOPE_AGENT);
    while ((unsigned)(sv >> 32) != tag && budget > 0) {
        __builtin_amdgcn_s_sleep(1);
        sv = __hip_atomic_load(sent, __ATOMIC_RELAXED, __HIP_MEMORY_SCOPE_AGENT);
        --budget;
    }
    return poll1(p, tag, budget);
}

// A-fragment packs: wp[((s*16+w)*16 + f)*64 + lane], f = rt*2 + ktl.
// row r = s*128 + rt*16 + (lane&15); pair kp = 32w + ktl*16 + (lane>>4)*4 + d.
// L0 (w<10): kp<64 -> x pair kp (Wih0), else h0 pair kp-64 (Whh0); w>=10 zero.
// L1: kp<256 -> Wih1, else Whh1 (kp-256).
#define NWPF (4 * 16 * 16 * 64)

__global__ void init_pack(const float* __restrict__ Wih0, const float* __restrict__ Whh0,
                          const float* __restrict__ Wih1, const float* __restrict__ Whh1,
                          uint4* __restrict__ wp0, uint4* __restrict__ wp1,
                          int* __restrict__ prog) {
    int gid = blockIdx.x * 256 + threadIdx.x;
    if (gid == 32) prog[32] = prog[32] + 1;   // epoch bump (replay-unique tags)
    if (gid < 32) prog[gid] = 0;
    if (gid < NWPF) {
        int lane = gid & 63, f = (gid >> 6) & 15, w = (gid >> 10) & 15, s = gid >> 14;
        uint4 o = make_uint4(0, 0, 0, 0);
        if (w < 10) {
            int rt = f >> 1, ktl = f & 1;
            int r = s * 128 + rt * 16 + (lane & 15);
            unsigned dv[4];
#pragma unroll
            for (int d = 0; d < 4; ++d) {
                int kp = 32 * w + ktl * 16 + ((lane >> 4) * 4) + d;
                float w0, w1;
                if (kp < 64) { w0 = Wih0[r * 128 + 2 * kp]; w1 = Wih0[r * 128 + 2 * kp + 1]; }
                else { int p0 = kp - 64;
                       w0 = Whh0[r * 512 + 2 * p0]; w1 = Whh0[r * 512 + 2 * p0 + 1]; }
                dv[d] = pack2(w0, w1);
            }
            o = make_uint4(dv[0], dv[1], dv[2], dv[3]);
        }
        wp0[gid] = o;
    } else if (gid < 2 * NWPF) {
        int idx = gid - NWPF;
        int lane = idx & 63, f = (idx >> 6) & 15, w = (idx >> 10) & 15, s = idx >> 14;
        int rt = f >> 1, ktl = f & 1;
        int r = s * 128 + rt * 16 + (lane & 15);
        unsigned dv[4];
#pragma unroll
        for (int d = 0; d < 4; ++d) {
            int kp = 32 * w + ktl * 16 + ((lane >> 4) * 4) + d;
            float w0, w1;
            if (kp < 256) { w0 = Wih1[r * 512 + 2 * kp]; w1 = Wih1[r * 512 + 2 * kp + 1]; }
            else { int p1 = kp - 256;
                   w0 = Whh1[r * 512 + 2 * p1]; w1 = Whh1[r * 512 + 2 * p1 + 1]; }
            dv[d] = pack2(w0, w1);
        }
        wp1[idx] = make_uint4(dv[0], dv[1], dv[2], dv[3]);
    }
}

template <int LAYER>
__device__ __forceinline__ void run_layer(
    int b0, int s, int L, int pair,
    const float* __restrict__ x, const float* __restrict__ noise,
    const uint4* __restrict__ wp,
    const float* __restrict__ bih, const float* __restrict__ bhh,
    unsigned long long* __restrict__ hb0, unsigned long long* __restrict__ hb1,
    int* __restrict__ prog,
    const float* __restrict__ fcw, const float* __restrict__ fcb,
    float* __restrict__ out) {
    constexpr int NP = (LAYER == 0) ? 10 : 16;      // active waves / psum groups

    const int w = L >> 6, lane = L & 63;
    const int j31 = lane & 31, bbl = lane >> 5;     // stage sub-roles
    const unsigned tagbase = ((unsigned)prog[32]) << 10;
    long budget = 2000000000L;

    // role flags (wave-uniform)
    const bool active   = (LAYER == 1) || (w < 10);
    const bool isX      = (LAYER == 0) && (w < 2);
    const bool isPF     = (LAYER == 1) && (w < 8);
    const bool isOwn    = (LAYER == 0) ? (w == 2 + 2 * s || w == 3 + 2 * s)
                                       : (w == 8 + 2 * s || w == 9 + 2 * s);
    const bool isRemote = active && !isX && !isPF && !isOwn;

    // ---- persistent A-fragments (16 x uint4 = 64 VGPRs) ----
    uint4 wfr[16];
#pragma unroll
    for (int f = 0; f < 16; ++f) {
        wfr[f] = wp[(size_t)(((s * 16 + w) * 16) + f) * 64 + lane];
        asm volatile("" : "+v"(wfr[f].x), "+v"(wfr[f].y), "+v"(wfr[f].z), "+v"(wfr[f].w));
    }

    __shared__ __align__(16) unsigned strip[16][64];   // per-wave k-block [b*32 + kp_local]
    __shared__ __align__(16) float psum[NP][2][128];   // [group][batch][row]
    for (int i = L; i < 16 * 64; i += 1024) ((unsigned*)strip)[i] = 0u;  // h(-1)=0

    // reduce-role constants (lanes 0..255)
    const bool isRed = (L < 256);
    const int bbr = L >> 7, rw = L & 127;
    const int rgl = s * 128 + rw;
    float cb = 0.f, nz = 0.f;
    if (isRed) {
        cb = bih[rgl] + bhh[rgl];
        nz = ntload_f(&noise[(((size_t)(b0 + bbr) * T_STEPS + 0) * 2 + LAYER) * 512 + rgl]);
    }
    __syncthreads();

    // ---- pre-loop staging ----
    unsigned long long pf = 0;
    float2 xf = make_float2(0.f, 0.f);
    if constexpr (LAYER == 1) {
        if (isPF) {   // h0(0): sentinel-paced blocking poll (L0 computes it in step 0)
            unsigned long long* base = &hb0[((size_t)0 * NBATCH + (b0 + bbl)) * 256];
            unsigned v = poll_sent(base + (32 * w + j31), base + (32 * w + 31),
                                   tagbase + 1, budget);
            pf = ((unsigned long long)(tagbase + 1) << 32) | v;
        }
    } else {
        if (isX)
            xf = ntload_f2(x + ((size_t)(b0 + bbl) * T_STEPS + 0) * 128 + 2 * (32 * w + j31));
    }

    int known = 0;
    const int colm = lane & 15, kg = lane >> 4;

    for (int t = 0; t < T_STEPS; ++t) {
        const bool last = (t == T_STEPS - 1);
        __builtin_amdgcn_s_setprio(1);

        // ---- STAGE own k-block into own strip ----
        if constexpr (LAYER == 1) {
            if (isPF) {                                   // h0(t): pf pipeline
                unsigned want = tagbase + (unsigned)t + 1;
                if ((unsigned)(pf >> 32) != want) {
                    __builtin_amdgcn_s_setprio(0);
                    unsigned long long* base =
                        &hb0[((size_t)(t & (DRING - 1)) * NBATCH + (b0 + bbl)) * 256];
                    unsigned v = poll_sent(base + (32 * w + j31), base + (32 * w + 31),
                                           want, budget);
                    pf = ((unsigned long long)want << 32) | v;
                    __builtin_amdgcn_s_setprio(1);
                }
                strip[w][bbl * 32 + j31] = (unsigned)pf;
                if (!last)
                    pf = __hip_atomic_load(&hb0[((size_t)((t + 1) & (DRING - 1)) * NBATCH +
                                                 (b0 + bbl)) * 256 + (32 * w + j31)],
                                           __ATOMIC_RELAXED, __HIP_MEMORY_SCOPE_AGENT);
            } else if (isRemote) {                        // remote h1(t-1)
                if (t > 0) {
                    unsigned long long* base =
                        &hb1[((size_t)((t - 1) & 3) * NBATCH + (b0 + bbl)) * 256];
                    __builtin_amdgcn_s_setprio(0);
                    unsigned v = poll_sent(base + (32 * (w - 8) + j31),
                                           base + (32 * (w - 8) + 31),
                                           tagbase + (unsigned)t, budget);
                    __builtin_amdgcn_s_setprio(1);
                    strip[w][bbl * 32 + j31] = v;
                }
            }                                             // own: filled by reduce(t-1)
        } else {
            if (isX) {                                    // x(t) pack + x(t+1) nt-load
                strip[w][bbl * 32 + j31] = pack2(xf.x, xf.y);
                if (!last)
                    xf = ntload_f2(x + ((size_t)(b0 + bbl) * T_STEPS + (t + 1)) * 128 +
                                   2 * (32 * w + j31));
            } else if (isRemote) {                        // remote h0(t-1)
                if (t > 0) {
                    unsigned long long* base =
                        &hb0[((size_t)((t - 1) & (DRING - 1)) * NBATCH + (b0 + bbl)) * 256];
                    __builtin_amdgcn_s_setprio(0);
                    unsigned v = poll_sent(base + (32 * w - 64 + j31),
                                           base + (32 * w - 64 + 31),
                                           tagbase + (unsigned)t, budget);
                    __builtin_amdgcn_s_setprio(1);
                    strip[w][bbl * 32 + j31] = v;
                }
            }                                             // own: filled by reduce(t-1)
        }

        float nznext = 0.f;
        if (!last && isRed)
            nznext = ntload_f(&noise[(((size_t)(b0 + bbr) * T_STEPS + (t + 1)) * 2 + LAYER) * 512 + rgl]);

        // ---- MFMA: this wave's 2 k-tiles over all 8 row-tiles (no bar_s) ----
        if (active) {
            const unsigned* sb = &strip[w][(colm & 1) * 32 + kg * 4];
            uint4 B0 = *(const uint4*)&sb[0];             // ktl=0 (within-wave w->r order)
            uint4 B1 = *(const uint4*)&sb[16];            // ktl=1
#pragma unroll
            for (int rt = 0; rt < 8; ++rt) {
                f32x4 C = {0.f, 0.f, 0.f, 0.f};
                C = mfma16(wfr[2 * rt + 0], B0, C);
                C = mfma16(wfr[2 * rt + 1], B1, C);
                if (colm < 2)
                    *(f32x4*)&psum[w][colm][rt * 16 + 4 * kg] = C;
            }
        }

        bar_lgkm();                                       // bar_b: psum ready

        // ---- reduce + tanh + post + write own pairs into owner strips ----
        if (isRed) {
            float sum = 0.f;
#pragma unroll
            for (int g = 0; g < NP; ++g) sum += psum[g][bbr][rw];
            float h = fast_tanh(sum + cb + nz);
            float hnb = __shfl_down(h, 1);
            if ((L & 1) == 0) {
                unsigned pv = pack2(h, hnb);
                int pr = s * 64 + (rw >> 1);              // pair index 0..255
                unsigned long long atom =
                    ((unsigned long long)(tagbase + (unsigned)t + 1) << 32) |
                    (unsigned long long)pv;
                if constexpr (LAYER == 0) {
                    if (t - known > THR_LEAD) {           // ring-overwrite throttle
                        __builtin_amdgcn_s_setprio(0);
                        while (t - known > THR_LEAD && budget > 0) {
                            __builtin_amdgcn_s_sleep(2);
                            known = __hip_atomic_load(&prog[pair], __ATOMIC_RELAXED,
                                                      __HIP_MEMORY_SCOPE_AGENT);
                            --budget;
                        }
                        __builtin_amdgcn_s_setprio(1);
                    }
                    __hip_atomic_store(&hb0[((size_t)(t & (DRING - 1)) * NBATCH + (b0 + bbr)) * 256 + pr],
                                       atom, __ATOMIC_RELAXED, __HIP_MEMORY_SCOPE_AGENT);
                    strip[2 + (pr >> 5)][bbr * 32 + (pr & 31)] = pv;   // own-h0 owner strip
                } else {
                    __hip_atomic_store(&hb1[((size_t)(t & 3) * NBATCH + (b0 + bbr)) * 256 + pr],
                                       atom, __ATOMIC_RELAXED, __HIP_MEMORY_SCOPE_AGENT);
                    strip[8 + (pr >> 5)][bbr * 32 + (pr & 31)] = pv;   // own-h1 owner strip
                }
            }
            nz = nznext;
        }
        if constexpr (LAYER == 1) {                       // consumer progress
            if (s == 0 && L == 960 && t > 1)
                __hip_atomic_store(&prog[pair], t - 2, __ATOMIC_RELAXED,
                                   __HIP_MEMORY_SCOPE_AGENT);
        }
        bar_lgkm();                                       // bar_c: strips/psum sealed
        __builtin_amdgcn_s_setprio(0);
    }

    // ---- FC epilogue: out = h1(T-1) @ fc_w^T + fc_b (L1 s==0 WGs) ----
    if constexpr (LAYER == 1) {
        if (s == 0) {
            __shared__ float hs[2][512];
            __shared__ float part[2][512];
            if (L < 512) {
                int bl = L >> 8, pr = L & 255;
                unsigned v = poll1(&hb1[((size_t)((T_STEPS - 1) & 3) * NBATCH + (b0 + bl)) * 256 + pr],
                                   tagbase + (unsigned)T_STEPS, budget);
                half2v h2 = __builtin_bit_cast(half2v, v);
                hs[bl][2 * pr] = (float)h2.x; hs[bl][2 * pr + 1] = (float)h2.y;
            }
            __syncthreads();
            {
                int bl = L >> 9, rest = L & 511, o = rest & 31, seg = rest >> 5;
                const float* wr = fcw + o * 512 + seg * 32;
                const float* hr = &hs[bl][seg * 32];
                float a = 0.f;
#pragma unroll
                for (int k = 0; k < 32; ++k) a = fmaf(wr[k], hr[k], a);
                part[bl][rest] = a;
            }
            __syncthreads();
            if (L < 64) {
                int bl = L >> 5, o = L & 31;
                float ssum = fcb[o];
#pragma unroll
                for (int sgi = 0; sgi < 16; ++sgi) ssum += part[bl][sgi * 32 + o];
                out[(b0 + bl) * 32 + o] = ssum;
            }
        }
    }
}

__global__ __launch_bounds__(1024, 4)
void rnn_dual(const float* __restrict__ x, const float* __restrict__ noise,
              const uint4* __restrict__ wp0, const uint4* __restrict__ wp1,
              const float* __restrict__ bih0, const float* __restrict__ bhh0,
              const float* __restrict__ bih1, const float* __restrict__ bhh1,
              const float* __restrict__ fcw, const float* __restrict__ fcb,
              unsigned long long* __restrict__ hb0,
              unsigned long long* __restrict__ hb1,
              int* __restrict__ prog,
              float* __restrict__ out) {
    const int L = threadIdx.x;
    const int gid = blockIdx.x;
    const int cl = gid & 63;             // cluster: layer*32 + pair
    const int s = gid >> 6;              // sibling quarter 0..3
    const int layer = cl >> 5;
    const int pair = cl & 31;
    const int b0 = pair * 2;             // gid%8 == cl%8: co-XCD (locality only)
    if (layer == 0)
        run_layer<0>(b0, s, L, pair, x, noise, wp0, bih0, bhh0,
                     hb0, hb1, prog, nullptr, nullptr, nullptr);
    else
        run_layer<1>(b0, s, L, pair, x, noise, wp1, bih1, bhh1,
                     hb0, hb1, prog, fcw, fcb, out);
}

extern "C" void kernel_launch(void* const* d_in, const int* in_sizes, int n_in,
                              void* d_out, int out_size, void* d_ws, size_t ws_size,
                              hipStream_t stream) {
    const float* x     = (const float*)d_in[0];
    const float* noise = (const float*)d_in[1];
    const float* Wih0  = (const float*)d_in[2];
    const float* Wih1  = (const float*)d_in[3];
    const float* Whh0  = (const float*)d_in[4];
    const float* Whh1  = (const float*)d_in[5];
    const float* bih0  = (const float*)d_in[6];
    const float* bih1  = (const float*)d_in[7];
    const float* bhh0  = (const float*)d_in[8];
    const float* bhh1  = (const float*)d_in[9];
    const float* fcw   = (const float*)d_in[10];
    const float* fcb   = (const float*)d_in[11];
    float* out = (float*)d_out;

    char* ws = (char*)d_ws;
    size_t o = 0;
    uint4* wp0 = (uint4*)(ws + o); o += (size_t)NWPF * 16;      // 1 MB
    uint4* wp1 = (uint4*)(ws + o); o += (size_t)NWPF * 16;      // 1 MB
    unsigned long long* hb0 = (unsigned long long*)(ws + o);
    o += (size_t)DRING * NBATCH * 256 * 8;                      // 4.2 MB ring (L3-hot)
    unsigned long long* hb1 = (unsigned long long*)(ws + o);
    o += (size_t)4 * NBATCH * 256 * 8;                          // 512 KB ring
    int* prog = (int*)(ws + o); o += 33 * sizeof(int);          // prog + epoch

    const int total = 2 * NWPF;
    init_pack<<<(total + 255) / 256, 256, 0, stream>>>(Wih0, Whh0, Wih1, Whh1,
                                                       wp0, wp1, prog);
    rnn_dual<<<256, 1024, 0, stream>>>(x, noise, wp0, wp1, bih0, bhh0, bih1, bhh1,
                                       fcw, fcb, hb0, hb1, prog, out);
}